// Round 2
// baseline (395.537 us; speedup 1.0000x reference)
//
#include <hip/hip_runtime.h>

// SoftHistLoss: x,y [16,3,512,512] f32 -> scalar f32
// w_i(v) = sigma(150(v-e_i)) - sigma(150(v-e_{i+1})), e_j = j/10.
// Pixel with k=floor(10v): (1-a)->bin k-1, (a-b)->bin k, b->bin k+1,
// a = sigma(150(v-e_k)) with arg in [0,15], b = sigma(arg-15). Tails < 3.1e-7/px.
// LDS: hist[12][256] (stored bin = real bin + 1; rows 0 and 11 are dead edges,
// so no edge branches). ds_add_f32 bank = t%32 -> conflict-free.

static constexpr int PLANES   = 48;          // 16*3 per image
static constexpr int PLANE_PX = 512 * 512;
static constexpr int SPP      = 32;          // sub-blocks per plane
static constexpr int THREADS  = 256;
static constexpr int CHUNK    = PLANE_PX / SPP;   // 8192 px/block
static constexpr int NB       = 12;          // stored bins -1..10

__global__ __launch_bounds__(THREADS, 8) void soft_hist_partial(
    const float* __restrict__ xin, const float* __restrict__ yin,
    float* __restrict__ G /* [96][10] */)
{
  __shared__ float hist[NB * THREADS];       // 12288 B
  const int t = threadIdx.x;
  #pragma unroll
  for (int s = 0; s < NB; ++s) hist[s * THREADS + t] = 0.0f;
  __syncthreads();

  const int blk   = blockIdx.x;
  const int plane = blk >> 5;                // 0..95 (0..47 = x, 48..95 = y)
  const int sub   = blk & 31;
  const float* src = (plane < PLANES ? xin + (size_t)plane * PLANE_PX
                                     : yin + (size_t)(plane - PLANES) * PLANE_PX)
                   + (size_t)sub * CHUNK;
  const float4* src4 = (const float4*)src;

  constexpr int ITERS = CHUNK / (THREADS * 4);    // 8
  #pragma unroll
  for (int it = 0; it < ITERS; ++it) {
    float4 v4 = src4[it * THREADS + t];
    float vv[4] = {v4.x, v4.y, v4.z, v4.w};
    #pragma unroll
    for (int j = 0; j < 4; ++j) {
      float v  = vv[j];
      float kf = floorf(v * 10.0f);
      kf = fminf(fmaxf(kf, 0.0f), 9.0f);
      int   k  = (int)kf;
      float xx = fmaf(-15.0f, kf, 150.0f * v);    // 150(v - e_k) in [0,15]
      float ex = __expf(-xx);
      float ey = ex * 3269017.3724721107f;        // exp(15-xx)*exp(-15)... = exp(-(xx-15))
      float a  = __builtin_amdgcn_rcpf(1.0f + ex);   // sigma(xx)
      float b  = __builtin_amdgcn_rcpf(1.0f + ey);   // sigma(xx-15)
      float* p = hist + k * THREADS + t;
      atomicAdd(p,               1.0f - a);     // -> real bin k-1 (stored k)
      atomicAdd(p + THREADS,     a - b);        // -> real bin k   (stored k+1)
      atomicAdd(p + 2 * THREADS, b);            // -> real bin k+1 (stored k+2)
    }
  }
  __syncthreads();

  // per-wave shuffle reduce of stored bins 1..10 over the wave's 64 columns
  const int lane = t & 63, w = t >> 6;
  float r[10];
  #pragma unroll
  for (int s = 0; s < 10; ++s) r[s] = hist[(s + 1) * THREADS + t];
  #pragma unroll
  for (int off = 32; off >= 1; off >>= 1) {
    #pragma unroll
    for (int s = 0; s < 10; ++s) r[s] += __shfl_xor(r[s], off, 64);
  }
  __syncthreads();                           // hist rows now dead for reuse
  if (lane == 0) {
    #pragma unroll
    for (int s = 0; s < 10; ++s) hist[w * 16 + s] = r[s];
  }
  __syncthreads();
  if (t < 10) {
    float sum = hist[t] + hist[16 + t] + hist[32 + t] + hist[48 + t];
    atomicAdd(&G[plane * 10 + t], sum);
  }
}

__global__ __launch_bounds__(512) void soft_hist_loss(
    const float* __restrict__ G, float* __restrict__ out)
{
  __shared__ float red[512];
  const int t = threadIdx.x;
  float val = 0.0f;
  if (t < 480) {
    const int pc = t / 10;        // (batch,channel) 0..47
    const int i  = t - pc * 10;   // bin
    val = fabsf(G[pc * 10 + i] - G[(pc + PLANES) * 10 + i]);
  }
  red[t] = val;
  __syncthreads();
  for (int s = 256; s > 0; s >>= 1) {
    if (t < s) red[t] += red[t + s];
    __syncthreads();
  }
  // loss = sum * (1/BINS) * (1/B) * 1e-4
  if (t == 0) out[0] = red[0] * 6.25e-7f;
}

extern "C" void kernel_launch(void* const* d_in, const int* in_sizes, int n_in,
                              void* d_out, int out_size, void* d_ws, size_t ws_size,
                              hipStream_t stream) {
  const float* x = (const float*)d_in[0];
  const float* y = (const float*)d_in[1];
  float* G = (float*)d_ws;                   // 96*10*4 = 3840 B
  hipMemsetAsync(d_ws, 0, 96 * 10 * sizeof(float), stream);
  soft_hist_partial<<<96 * SPP, THREADS, 0, stream>>>(x, y, G);
  soft_hist_loss<<<1, 512, 0, stream>>>(G, (float*)d_out);
}

// Round 3
// 55.208 us; speedup vs baseline: 7.1645x; 7.1645x over previous
//
#include <hip/hip_runtime.h>

// SoftHistLoss: x,y [16,3,512,512] f32 -> scalar f32
// w_i(v) = sigma(150(v-e_i)) - sigma(150(v-e_{i+1})), e_j = j/10.
// Pixel with k = floor(10v) clamped to [0,9]: only nontrivial sigmoids are
// a = sigma(xx), b = sigma(xx-15), xx = 150(v - e_k) in [0,15]; tails < 3.1e-7.
// Accumulate per-bin A[k]=sum a, B[k]=sum b, C[k]=count -- ALL at row k, so one
// float4 LDS slot RMW per pixel (non-atomic: thread t owns column t).
// Recombine: hist_i = C[i+1] + A[i] + B[i-1] - A[i+1] - B[i].

static constexpr int PLANES   = 48;               // 16*3 per image
static constexpr int PLANE_PX = 512 * 512;
static constexpr int SPP      = 32;               // sub-blocks per plane
static constexpr int THREADS  = 256;
static constexpr int CHUNK    = PLANE_PX / SPP;   // 8192 px per block
static constexpr float E15    = 3269017.3724721107f;  // e^15

__global__ __launch_bounds__(THREADS, 4) void soft_hist_partial(
    const float* __restrict__ xin, const float* __restrict__ yin,
    float* __restrict__ G /* [96][30] : per-plane {A,B,C} x 10 bins */)
{
  __shared__ __align__(16) float4 slot[10][THREADS];   // 40960 B -> 4 blocks/CU
  const int t = threadIdx.x;
  #pragma unroll
  for (int s = 0; s < 10; ++s) slot[s][t] = float4{0.f, 0.f, 0.f, 0.f};
  __syncthreads();

  const int blk   = blockIdx.x;
  const int plane = blk >> 5;                 // 0..95 (0..47 = x, 48..95 = y)
  const int sub   = blk & 31;
  const float* src = (plane < PLANES ? xin + (size_t)plane * PLANE_PX
                                     : yin + (size_t)(plane - PLANES) * PLANE_PX)
                   + (size_t)sub * CHUNK;
  const float4* src4 = (const float4*)src;

  constexpr int ITERS = CHUNK / (THREADS * 4);  // 8
  #pragma unroll
  for (int it = 0; it < ITERS; ++it) {
    float4 v4 = src4[it * THREADS + t];
    float vv[4] = {v4.x, v4.y, v4.z, v4.w};
    #pragma unroll
    for (int j = 0; j < 4; ++j) {
      float v  = vv[j];
      float kf = floorf(v * 10.0f);
      kf = fminf(fmaxf(kf, 0.0f), 9.0f);
      int   k  = (int)kf;
      float xx = fmaf(-15.0f, kf, 150.0f * v);        // 150(v - e_k) in [0,15]
      float ex = __expf(-xx);
      float t1 = 1.0f + ex;                           // 1/sigma(xx)
      float t2 = fmaf(E15, ex, 1.0f);                 // 1/sigma(xx-15)
      float r  = __builtin_amdgcn_rcpf(t1 * t2);      // one rcp, two sigmoids
      float a  = r * t2;                              // sigma(xx)
      float b  = r * t1;                              // sigma(xx-15)
      float4* p = &slot[k][t];
      float4 o = *p;                                  // ds_read_b128
      o.x += a; o.y += b; o.z += 1.0f;
      *p = o;                                         // ds_write_b128
    }
  }
  __syncthreads();

  // cross-column reduce: butterfly over each wave's 64 lanes, 10 bins x 3 comps
  const int lane = t & 63, w = t >> 6;
  float rx[10], ry[10], rz[10];
  #pragma unroll
  for (int s = 0; s < 10; ++s) {
    float4 q = slot[s][t];
    rx[s] = q.x; ry[s] = q.y; rz[s] = q.z;
  }
  #pragma unroll
  for (int off = 32; off >= 1; off >>= 1) {
    #pragma unroll
    for (int s = 0; s < 10; ++s) {
      rx[s] += __shfl_xor(rx[s], off, 64);
      ry[s] += __shfl_xor(ry[s], off, 64);
      rz[s] += __shfl_xor(rz[s], off, 64);
    }
  }
  __syncthreads();
  float* red = (float*)slot;                    // reuse LDS
  if (lane == 0) {
    #pragma unroll
    for (int s = 0; s < 10; ++s) {
      red[(w * 10 + s) * 4 + 0] = rx[s];
      red[(w * 10 + s) * 4 + 1] = ry[s];
      red[(w * 10 + s) * 4 + 2] = rz[s];
    }
  }
  __syncthreads();
  if (t < 30) {                                 // t = 3k + c
    const int k = t / 3, c = t - k * 3;
    float s0 = red[(0 * 10 + k) * 4 + c] + red[(1 * 10 + k) * 4 + c]
             + red[(2 * 10 + k) * 4 + c] + red[(3 * 10 + k) * 4 + c];
    atomicAdd(&G[plane * 30 + t], s0);          // global f32 atomic: 30/block
  }
}

__global__ __launch_bounds__(512) void soft_hist_loss(
    const float* __restrict__ G, float* __restrict__ out)
{
  __shared__ float red[512];
  const int t = threadIdx.x;
  float val = 0.0f;
  if (t < 480) {
    const int pc = t / 10;        // (batch,channel) 0..47
    const int i  = t - pc * 10;   // bin
    const float* gx = G + pc * 30;
    const float* gy = G + (pc + PLANES) * 30;
    // hist_i = A[i] - B[i] + (C[i+1] - A[i+1]) + B[i-1]
    float hx = gx[3 * i] - gx[3 * i + 1]
             + (i < 9 ? gx[3 * (i + 1) + 2] - gx[3 * (i + 1)] : 0.0f)
             + (i > 0 ? gx[3 * (i - 1) + 1] : 0.0f);
    float hy = gy[3 * i] - gy[3 * i + 1]
             + (i < 9 ? gy[3 * (i + 1) + 2] - gy[3 * (i + 1)] : 0.0f)
             + (i > 0 ? gy[3 * (i - 1) + 1] : 0.0f);
    val = fabsf(hx - hy);
  }
  red[t] = val;
  __syncthreads();
  for (int s = 256; s > 0; s >>= 1) {
    if (t < s) red[t] += red[t + s];
    __syncthreads();
  }
  // loss = sum * (1/BINS) * (1/B) * 1e-4
  if (t == 0) out[0] = red[0] * 6.25e-7f;
}

extern "C" void kernel_launch(void* const* d_in, const int* in_sizes, int n_in,
                              void* d_out, int out_size, void* d_ws, size_t ws_size,
                              hipStream_t stream) {
  const float* x = (const float*)d_in[0];
  const float* y = (const float*)d_in[1];
  float* G = (float*)d_ws;                      // 96*30*4 = 11520 B
  hipMemsetAsync(d_ws, 0, 96 * 30 * sizeof(float), stream);
  soft_hist_partial<<<96 * SPP, THREADS, 0, stream>>>(x, y, G);
  soft_hist_loss<<<1, 512, 0, stream>>>(G, (float*)d_out);
}

// Round 4
// 32.194 us; speedup vs baseline: 12.2859x; 1.7148x over previous
//
#include <hip/hip_runtime.h>

// SoftHistLoss: x,y [16,3,512,512] f32 -> scalar f32
// w_i(v) = sigma(150(v-e_i)) - sigma(150(v-e_{i+1})), e_j = j/10.
// Pixel with k = floor(10v): only nontrivial sigmoids are a = sigma(xx),
// b = sigma(xx-15), xx = 150(v - e_k) in [0,15]; dropped tails < 3.1e-7/px.
// hist_i = A[i] - B[i] + B[i-1] + (C[i+1] - A[i+1]),  A=sum a, B=sum b, C=count.
// Per pixel: ONE native LDS atomic (ds_add_u32) of a packed fixed-point word:
//   bits[31:17] = round(a*512)  (col sum <= 32*512  = 16384 < 2^15)
//   bits[16: 6] = round(b*64)   (col sum <= 32*32   = 1024  < 2^11)
//   bits[ 5: 0] = 1             (col sum <= 32            < 2^6)
// Thread t owns column t -> bank = t%32, data-independent, conflict-free.
// Quantization error ~1 count vs ~1461-count error budget.

static constexpr int PLANES   = 48;               // 16*3 per image
static constexpr int PLANE_PX = 512 * 512;
static constexpr int SPP      = 32;               // sub-blocks per plane
static constexpr int THREADS  = 256;
static constexpr int CHUNK    = PLANE_PX / SPP;   // 8192 px per block -> 32 px/thread
static constexpr float E15    = 3269017.3724721107f;  // e^15

__global__ __launch_bounds__(THREADS, 8) void soft_hist_partial(
    const float* __restrict__ xin, const float* __restrict__ yin,
    unsigned* __restrict__ G /* [96][32] u32: per plane {A,B,C} x 10 bins */)
{
  __shared__ unsigned hist[10 * THREADS];         // 10240 B
  __shared__ unsigned red[10 * 16 * 3];           // 1920 B
  const int t = threadIdx.x;
  #pragma unroll
  for (int s = 0; s < 10; ++s) hist[s * THREADS + t] = 0u;
  __syncthreads();

  const int blk   = blockIdx.x;
  const int plane = blk >> 5;                     // 0..95 (0..47 = x, 48..95 = y)
  const int sub   = blk & 31;
  const float* src = (plane < PLANES ? xin + (size_t)plane * PLANE_PX
                                     : yin + (size_t)(plane - PLANES) * PLANE_PX)
                   + (size_t)sub * CHUNK;
  const float4* src4 = (const float4*)src;
  unsigned* mycol = hist + t;

  constexpr int ITERS = CHUNK / (THREADS * 4);    // 8
  #pragma unroll
  for (int it = 0; it < ITERS; ++it) {
    float4 v4 = src4[it * THREADS + t];
    float vv[4] = {v4.x, v4.y, v4.z, v4.w};
    #pragma unroll
    for (int j = 0; j < 4; ++j) {
      float wv = vv[j] * 10.0f;                   // [0,10)
      float kf = fminf(floorf(wv), 9.0f);
      int   k  = (int)kf;
      float d  = wv - kf;                         // [0,1]
      float ex = __expf(d * -15.0f);              // e^{-xx}, xx = 15d
      float t1 = 1.0f + ex;                       // 1/sigma(xx)
      float t2 = fmaf(E15, ex, 1.0f);             // 1/sigma(xx-15)
      float r  = __builtin_amdgcn_rcpf(t1 * t2);  // one rcp -> both sigmoids
      unsigned qa = (unsigned)fmaf(r * t2, 512.0f, 0.5f);  // round(a*512)
      unsigned qb = (unsigned)fmaf(r * t1, 64.0f, 0.5f);   // round(b*64)
      atomicAdd(&mycol[k << 8], (qa << 17) + (qb << 6) + 1u);  // ds_add_u32
    }
  }
  __syncthreads();

  // stage 1: 160 threads, each sums 16 columns of one bin (unpacked fields)
  if (t < 160) {
    const int bin = t >> 4, grp = t & 15;
    const uint4* hp = (const uint4*)(hist + (bin << 8) + (grp << 4));
    unsigned sa = 0, sb = 0, sc = 0;
    #pragma unroll
    for (int q = 0; q < 4; ++q) {
      uint4 u4 = hp[q];
      unsigned uu[4] = {u4.x, u4.y, u4.z, u4.w};
      #pragma unroll
      for (int e = 0; e < 4; ++e) {
        unsigned u = uu[e];
        sa += u >> 17; sb += (u >> 6) & 0x7FFu; sc += u & 0x3Fu;
      }
    }
    const int base = (bin * 16 + grp) * 3;
    red[base] = sa; red[base + 1] = sb; red[base + 2] = sc;
  }
  __syncthreads();

  // stage 2: 30 threads -> global integer atomics (deterministic)
  if (t < 30) {
    const int bin = t / 3, c = t - 3 * bin;
    unsigned s = 0;
    #pragma unroll
    for (int g = 0; g < 16; ++g) s += red[(bin * 16 + g) * 3 + c];
    atomicAdd(&G[plane * 32 + bin * 3 + c], s);
  }
}

__global__ __launch_bounds__(512) void soft_hist_loss(
    const unsigned* __restrict__ G, float* __restrict__ out)
{
  __shared__ float red[512];
  const int t = threadIdx.x;
  float val = 0.0f;
  if (t < 480) {
    const int pc = t / 10;        // (batch,channel) 0..47
    const int i  = t - pc * 10;   // bin
    const unsigned* gx = G + pc * 32;
    const unsigned* gy = G + (pc + PLANES) * 32;
    // hist_i = A[i]/512 - B[i]/64 + B[i-1]/64 + C[i+1] - A[i+1]/512
    float hx = (float)gx[3 * i] * (1.0f / 512.0f)
             - (float)gx[3 * i + 1] * (1.0f / 64.0f)
             + (i > 0 ? (float)gx[3 * (i - 1) + 1] * (1.0f / 64.0f) : 0.0f)
             + (i < 9 ? (float)gx[3 * (i + 1) + 2]
                      - (float)gx[3 * (i + 1)] * (1.0f / 512.0f) : 0.0f);
    float hy = (float)gy[3 * i] * (1.0f / 512.0f)
             - (float)gy[3 * i + 1] * (1.0f / 64.0f)
             + (i > 0 ? (float)gy[3 * (i - 1) + 1] * (1.0f / 64.0f) : 0.0f)
             + (i < 9 ? (float)gy[3 * (i + 1) + 2]
                      - (float)gy[3 * (i + 1)] * (1.0f / 512.0f) : 0.0f);
    val = fabsf(hx - hy);
  }
  red[t] = val;
  __syncthreads();
  for (int s = 256; s > 0; s >>= 1) {
    if (t < s) red[t] += red[t + s];
    __syncthreads();
  }
  // loss = sum * (1/BINS) * (1/B) * 1e-4
  if (t == 0) out[0] = red[0] * 6.25e-7f;
}

extern "C" void kernel_launch(void* const* d_in, const int* in_sizes, int n_in,
                              void* d_out, int out_size, void* d_ws, size_t ws_size,
                              hipStream_t stream) {
  const float* x = (const float*)d_in[0];
  const float* y = (const float*)d_in[1];
  unsigned* G = (unsigned*)d_ws;               // 96*32*4 = 12288 B
  hipMemsetAsync(d_ws, 0, 96 * 32 * sizeof(unsigned), stream);
  soft_hist_partial<<<96 * SPP, THREADS, 0, stream>>>(x, y, G);
  soft_hist_loss<<<1, 512, 0, stream>>>(G, (float*)d_out);
}

// Round 5
// 32.158 us; speedup vs baseline: 12.3000x; 1.0011x over previous
//
#include <hip/hip_runtime.h>

// SoftHistLoss: x,y [16,3,512,512] f32 -> scalar f32
// w_i(v) = sigma(150(v-e_i)) - sigma(150(v-e_{i+1})), e_j = j/10.
// Pixel with k = floor(10v): only nontrivial sigmoids are a = sigma(xx),
// b = sigma(xx-15), xx = 150(v - e_k) in [0,15]; dropped tails < 3.1e-7/px.
// hist_i = A[i] - B[i] + B[i-1] + (C[i+1] - A[i+1]),  A=sum a, B=sum b, C=count.
// Per pixel: ONE native LDS atomic (ds_add_u32) of a packed fixed-point word:
//   bits[31:17] = round(a*512)  (col sum <= 32*512 = 16384 < 2^15)
//   bits[16: 6] = round(b*64)   (col sum <= 32*32  = 1024  < 2^11)
//   bits[ 5: 0] = 1             (col sum <= 32           < 2^6)
// Thread t owns column t -> bank = t%32, data-independent, conflict-free.
// Each block OVERWRITES its own partial slot in G (no global atomics ->
// no pre-zeroing memset dispatch; poison-immune).

static constexpr int PLANES   = 48;               // 16*3 per image
static constexpr int PLANE_PX = 512 * 512;
static constexpr int SPP      = 32;               // sub-blocks per plane
static constexpr int THREADS  = 256;
static constexpr int CHUNK    = PLANE_PX / SPP;   // 8192 px per block -> 32 px/thread
static constexpr int NBLK     = 96 * SPP;         // 3072
static constexpr float E15    = 3269017.3724721107f;  // e^15

__global__ __launch_bounds__(THREADS, 8) void soft_hist_partial(
    const float* __restrict__ xin, const float* __restrict__ yin,
    unsigned* __restrict__ G /* [3072][32] u32: per-block {A,B,C} x 10 bins */)
{
  __shared__ unsigned hist[10 * THREADS];         // 10240 B
  __shared__ unsigned red[10 * 16 * 3];           // 1920 B
  const int t = threadIdx.x;
  #pragma unroll
  for (int s = 0; s < 10; ++s) hist[s * THREADS + t] = 0u;
  __syncthreads();

  const int blk   = blockIdx.x;
  const int plane = blk >> 5;                     // 0..95 (0..47 = x, 48..95 = y)
  const int sub   = blk & 31;
  const float* src = (plane < PLANES ? xin + (size_t)plane * PLANE_PX
                                     : yin + (size_t)(plane - PLANES) * PLANE_PX)
                   + (size_t)sub * CHUNK;
  const float4* src4 = (const float4*)src;
  unsigned* mycol = hist + t;

  constexpr int ITERS = CHUNK / (THREADS * 4);    // 8
  #pragma unroll
  for (int it = 0; it < ITERS; ++it) {
    float4 v4 = src4[it * THREADS + t];
    float vv[4] = {v4.x, v4.y, v4.z, v4.w};
    #pragma unroll
    for (int j = 0; j < 4; ++j) {
      float wv = vv[j] * 10.0f;                   // [0,10)
      float kf = fminf(floorf(wv), 9.0f);
      int   k  = (int)kf;
      float d  = wv - kf;                         // [0,1]
      float ex = __expf(d * -15.0f);              // e^{-xx}, xx = 15d
      float t1 = 1.0f + ex;                       // 1/sigma(xx)
      float t2 = fmaf(E15, ex, 1.0f);             // 1/sigma(xx-15)
      float r  = __builtin_amdgcn_rcpf(t1 * t2);  // one rcp -> both sigmoids
      unsigned qa = (unsigned)fmaf(r * t2, 512.0f, 0.5f);  // round(a*512)
      unsigned qb = (unsigned)fmaf(r * t1, 64.0f, 0.5f);   // round(b*64)
      atomicAdd(&mycol[k << 8], (qa << 17) + (qb << 6) + 1u);  // ds_add_u32
    }
  }
  __syncthreads();

  // stage 1: 160 threads, each sums 16 columns of one bin (unpacked fields)
  if (t < 160) {
    const int bin = t >> 4, grp = t & 15;
    const uint4* hp = (const uint4*)(hist + (bin << 8) + (grp << 4));
    unsigned sa = 0, sb = 0, sc = 0;
    #pragma unroll
    for (int q = 0; q < 4; ++q) {
      uint4 u4 = hp[q];
      unsigned uu[4] = {u4.x, u4.y, u4.z, u4.w};
      #pragma unroll
      for (int e = 0; e < 4; ++e) {
        unsigned u = uu[e];
        sa += u >> 17; sb += (u >> 6) & 0x7FFu; sc += u & 0x3Fu;
      }
    }
    const int base = (bin * 16 + grp) * 3;
    red[base] = sa; red[base + 1] = sb; red[base + 2] = sc;
  }
  __syncthreads();

  // stage 2: 30 threads -> plain per-block store (overwrite, no memset needed)
  if (t < 30) {
    const int bin = t / 3, c = t - 3 * bin;
    unsigned s = 0;
    #pragma unroll
    for (int g = 0; g < 16; ++g) s += red[(bin * 16 + g) * 3 + c];
    G[blk * 32 + bin * 3 + c] = s;
  }
}

__global__ __launch_bounds__(1024) void soft_hist_loss(
    const unsigned* __restrict__ G, float* __restrict__ out)
{
  __shared__ unsigned T[96 * 30];                 // per-plane {A,B,C}x10, 11520 B
  __shared__ float wred[16];
  const int t = threadIdx.x;

  // stage A: 2880 (plane,comp) items; each sums its comp over the 32 sub-blocks.
  // consecutive t = consecutive comp -> coalesced 120B runs, all L2-resident.
  for (int item = t; item < 96 * 30; item += 1024) {
    const int plane = item / 30, comp = item - plane * 30;
    const unsigned* g = G + (size_t)plane * (32 * 32) + comp;
    unsigned s = 0;
    #pragma unroll
    for (int sub = 0; sub < 32; ++sub) s += g[sub * 32];
    T[item] = s;
  }
  __syncthreads();

  // stage B: 480 (pc, bin) items -> |hx - hy|
  float val = 0.0f;
  if (t < 480) {
    const int pc = t / 10;        // (batch,channel) 0..47
    const int i  = t - pc * 10;   // bin
    const unsigned* gx = T + pc * 30;
    const unsigned* gy = T + (pc + PLANES) * 30;
    // hist_i = A[i]/512 - B[i]/64 + B[i-1]/64 + C[i+1] - A[i+1]/512
    float hx = (float)gx[3 * i] * (1.0f / 512.0f)
             - (float)gx[3 * i + 1] * (1.0f / 64.0f)
             + (i > 0 ? (float)gx[3 * (i - 1) + 1] * (1.0f / 64.0f) : 0.0f)
             + (i < 9 ? (float)gx[3 * (i + 1) + 2]
                      - (float)gx[3 * (i + 1)] * (1.0f / 512.0f) : 0.0f);
    float hy = (float)gy[3 * i] * (1.0f / 512.0f)
             - (float)gy[3 * i + 1] * (1.0f / 64.0f)
             + (i > 0 ? (float)gy[3 * (i - 1) + 1] * (1.0f / 64.0f) : 0.0f)
             + (i < 9 ? (float)gy[3 * (i + 1) + 2]
                      - (float)gy[3 * (i + 1)] * (1.0f / 512.0f) : 0.0f);
    val = fabsf(hx - hy);
  }
  #pragma unroll
  for (int off = 32; off >= 1; off >>= 1) val += __shfl_xor(val, off, 64);
  if ((t & 63) == 0) wred[t >> 6] = val;
  __syncthreads();
  if (t == 0) {
    float s = 0.0f;
    #pragma unroll
    for (int w = 0; w < 16; ++w) s += wred[w];
    // loss = sum * (1/BINS) * (1/B) * 1e-4
    out[0] = s * 6.25e-7f;
  }
}

extern "C" void kernel_launch(void* const* d_in, const int* in_sizes, int n_in,
                              void* d_out, int out_size, void* d_ws, size_t ws_size,
                              hipStream_t stream) {
  const float* x = (const float*)d_in[0];
  const float* y = (const float*)d_in[1];
  unsigned* G = (unsigned*)d_ws;               // 3072*32*4 = 393216 B
  soft_hist_partial<<<NBLK, THREADS, 0, stream>>>(x, y, G);
  soft_hist_loss<<<1, 1024, 0, stream>>>(G, (float*)d_out);
}

// Round 6
// 31.910 us; speedup vs baseline: 12.3954x; 1.0078x over previous
//
#include <hip/hip_runtime.h>

// SoftHistLoss: x,y [16,3,512,512] f32 -> scalar f32
// w_i(v) = sigma(150(v-e_i)) - sigma(150(v-e_{i+1})), e_j = j/10.
// Pixel with k = floor(10v): only nontrivial sigmoids are a = sigma(xx),
// b = sigma(xx-15), xx = 15*frac(10v) in [0,15]; dropped tails < 3.1e-7/px.
// hist_i = A[i] - B[i] + B[i-1] + (C[i+1] - A[i+1]),  A=sum a, B=sum b, C=count.
// Per pixel: ONE native LDS atomic (ds_add_u32) of a packed fixed-point word:
//   bits[31:17] = round(a*512)  (col sum <= 32*512 = 16384 < 2^15)
//   bits[16: 6] = round(b*64)   (col sum <= 32*32  = 1024  < 2^11)
//   bits[ 5: 0] = 1             (col sum <= 32           < 2^6)
// Thread t owns column t -> bank = t%32, data-independent, conflict-free.
// Inner loop software-pipelined with prefetch depth 2 (keeps >=2 dwordx4 in
// flight per wave; ~60 VGPR stays within the 64-VGPR / 8-wave occupancy bin).

static constexpr int PLANES   = 48;               // 16*3 per image
static constexpr int PLANE_PX = 512 * 512;
static constexpr int SPP      = 32;               // sub-blocks per plane
static constexpr int THREADS  = 256;
static constexpr int CHUNK    = PLANE_PX / SPP;   // 8192 px per block -> 32 px/thread
static constexpr int NBLK     = 96 * SPP;         // 3072
static constexpr float E15    = 3269017.3724721107f;  // e^15

__global__ __launch_bounds__(THREADS, 8) void soft_hist_partial(
    const float* __restrict__ xin, const float* __restrict__ yin,
    unsigned* __restrict__ G /* [96][30] u32: per plane {A,B,C} x 10 bins */)
{
  __shared__ unsigned hist[10 * THREADS];         // 10240 B
  __shared__ unsigned red[10 * 16 * 3];           // 1920 B
  const int t = threadIdx.x;
  #pragma unroll
  for (int s = 0; s < 10; ++s) hist[s * THREADS + t] = 0u;
  __syncthreads();

  const int blk   = blockIdx.x;
  const int plane = blk >> 5;                     // 0..95 (0..47 = x, 48..95 = y)
  const int sub   = blk & 31;
  const float* src = (plane < PLANES ? xin + (size_t)plane * PLANE_PX
                                     : yin + (size_t)(plane - PLANES) * PLANE_PX)
                   + (size_t)sub * CHUNK;
  const float4* src4 = (const float4*)src;
  unsigned* mycol = hist + t;

  constexpr int ITERS = CHUNK / (THREADS * 4);    // 8
  float4 c0 = src4[t];
  float4 c1 = src4[THREADS + t];
  #pragma unroll
  for (int it = 0; it < ITERS; ++it) {
    float4 cur = c0;
    c0 = c1;
    if (it + 2 < ITERS) c1 = src4[(it + 2) * THREADS + t];
    float vv[4] = {cur.x, cur.y, cur.z, cur.w};
    #pragma unroll
    for (int j = 0; j < 4; ++j) {
      float wv = vv[j] * 10.0f;                   // [0,10)
      float d  = wv - floorf(wv);                 // v_fract
      int   k  = (int)wv;                         // trunc == floor (wv >= 0)
      k = k > 9 ? 9 : k;                          // v_min_i32 safety clamp
      float ex = __expf(d * -15.0f);              // e^{-xx}, xx = 15d
      float t1 = 1.0f + ex;                       // 1/sigma(xx)
      float t2 = fmaf(E15, ex, 1.0f);             // 1/sigma(xx-15)
      float r  = __builtin_amdgcn_rcpf(t1 * t2);  // one rcp -> both sigmoids
      unsigned qa = (unsigned)fmaf(r * t2, 512.0f, 0.5f);  // round(a*512)
      unsigned qb = (unsigned)fmaf(r * t1, 64.0f, 0.5f);   // round(b*64)
      unsigned pk = (((qa << 11) + qb) << 6) + 1u;         // 2x v_lshl_add
      atomicAdd(&mycol[k << 8], pk);              // ds_add_u32, fire-and-forget
    }
  }
  __syncthreads();

  // stage 1: 160 threads, each sums 16 columns of one bin (unpacked fields)
  if (t < 160) {
    const int bin = t >> 4, grp = t & 15;
    const uint4* hp = (const uint4*)(hist + (bin << 8) + (grp << 4));
    unsigned sa = 0, sb = 0, sc = 0;
    #pragma unroll
    for (int q = 0; q < 4; ++q) {
      uint4 u4 = hp[q];
      unsigned uu[4] = {u4.x, u4.y, u4.z, u4.w};
      #pragma unroll
      for (int e = 0; e < 4; ++e) {
        unsigned u = uu[e];
        sa += u >> 17; sb += (u >> 6) & 0x7FFu; sc += u & 0x3Fu;
      }
    }
    const int base = (bin * 16 + grp) * 3;
    red[base] = sa; red[base + 1] = sb; red[base + 2] = sc;
  }
  __syncthreads();

  // stage 2: 30 threads -> global integer atomics (deterministic)
  if (t < 30) {
    const int bin = t / 3, c = t - 3 * bin;
    unsigned s = 0;
    #pragma unroll
    for (int g = 0; g < 16; ++g) s += red[(bin * 16 + g) * 3 + c];
    atomicAdd(&G[plane * 30 + bin * 3 + c], s);
  }
}

__global__ __launch_bounds__(512) void soft_hist_loss(
    const unsigned* __restrict__ G, float* __restrict__ out)
{
  __shared__ float wred[8];
  const int t = threadIdx.x;
  float val = 0.0f;
  if (t < 480) {
    const int pc = t / 10;        // (batch,channel) 0..47
    const int i  = t - pc * 10;   // bin
    const unsigned* gx = G + pc * 30;
    const unsigned* gy = G + (pc + PLANES) * 30;
    // hist_i = A[i]/512 - B[i]/64 + B[i-1]/64 + C[i+1] - A[i+1]/512
    float hx = (float)gx[3 * i] * (1.0f / 512.0f)
             - (float)gx[3 * i + 1] * (1.0f / 64.0f)
             + (i > 0 ? (float)gx[3 * (i - 1) + 1] * (1.0f / 64.0f) : 0.0f)
             + (i < 9 ? (float)gx[3 * (i + 1) + 2]
                      - (float)gx[3 * (i + 1)] * (1.0f / 512.0f) : 0.0f);
    float hy = (float)gy[3 * i] * (1.0f / 512.0f)
             - (float)gy[3 * i + 1] * (1.0f / 64.0f)
             + (i > 0 ? (float)gy[3 * (i - 1) + 1] * (1.0f / 64.0f) : 0.0f)
             + (i < 9 ? (float)gy[3 * (i + 1) + 2]
                      - (float)gy[3 * (i + 1)] * (1.0f / 512.0f) : 0.0f);
    val = fabsf(hx - hy);
  }
  #pragma unroll
  for (int off = 32; off >= 1; off >>= 1) val += __shfl_xor(val, off, 64);
  if ((t & 63) == 0) wred[t >> 6] = val;
  __syncthreads();
  if (t == 0) {
    float s = 0.0f;
    #pragma unroll
    for (int w = 0; w < 8; ++w) s += wred[w];
    // loss = sum * (1/BINS) * (1/B) * 1e-4
    out[0] = s * 6.25e-7f;
  }
}

extern "C" void kernel_launch(void* const* d_in, const int* in_sizes, int n_in,
                              void* d_out, int out_size, void* d_ws, size_t ws_size,
                              hipStream_t stream) {
  const float* x = (const float*)d_in[0];
  const float* y = (const float*)d_in[1];
  unsigned* G = (unsigned*)d_ws;               // 96*30*4 = 11520 B
  hipMemsetAsync(d_ws, 0, 96 * 30 * sizeof(unsigned), stream);
  soft_hist_partial<<<NBLK, THREADS, 0, stream>>>(x, y, G);
  soft_hist_loss<<<1, 512, 0, stream>>>(G, (float*)d_out);
}

// Round 7
// 30.177 us; speedup vs baseline: 13.1072x; 1.0574x over previous
//
#include <hip/hip_runtime.h>

// SoftHistLoss: x,y [16,3,512,512] f32 -> scalar f32
// w_i(v) = sigma(150(v-e_i)) - sigma(150(v-e_{i+1})), e_j = j/10.
// Pixel with k = floor(10v): only nontrivial sigmoids are a = sigma(xx),
// b = sigma(xx-15), xx = 15*frac(10v); dropped tails < 3.1e-7/px.
// hist_i = A[i] - B[i] + B[i-1] + (C[i+1] - A[i+1]),  A=sum a, B=sum b, C=count.
// Per pixel: ONE native LDS atomic (ds_add_u32) of a packed fixed-point word:
//   bits[31:18] = round(a*255)  (col sum <= 64*255 = 16320 < 2^14)
//   bits[17: 7] = round(b*62)   (col sum <= 64*31  = 1984  < 2^11)
//   bits[ 6: 0] = 1             (col sum <= 64            < 2^7)
// Thread t owns column t -> bank = t%32, data-independent, conflict-free.
// R7: grid = 1536 blocks = EXACTLY 6 blocks/CU resident -> single occupancy
// round (R6's 3072 = 12/CU ran as 8+4 with a half-TLP tail). 64 px/thread.

static constexpr int PLANES   = 48;               // 16*3 per image
static constexpr int PLANE_PX = 512 * 512;
static constexpr int SPP      = 16;               // sub-blocks per plane
static constexpr int THREADS  = 256;
static constexpr int CHUNK    = PLANE_PX / SPP;   // 16384 px per block -> 64 px/thread
static constexpr int NBLK     = 96 * SPP;         // 1536 = 6 per CU
static constexpr float E15    = 3269017.3724721107f;  // e^15

__global__ __launch_bounds__(THREADS, 6) void soft_hist_partial(
    const float* __restrict__ xin, const float* __restrict__ yin,
    unsigned* __restrict__ G /* [96][30] u32: per plane {A,B,C} x 10 bins */)
{
  __shared__ unsigned hist[10 * THREADS];         // 10240 B
  __shared__ unsigned red[10 * 16 * 3];           // 1920 B
  const int t = threadIdx.x;
  #pragma unroll
  for (int s = 0; s < 10; ++s) hist[s * THREADS + t] = 0u;
  __syncthreads();

  const int blk   = blockIdx.x;
  const int plane = blk >> 4;                     // 0..95 (0..47 = x, 48..95 = y)
  const int sub   = blk & 15;
  const float* src = (plane < PLANES ? xin + (size_t)plane * PLANE_PX
                                     : yin + (size_t)(plane - PLANES) * PLANE_PX)
                   + (size_t)sub * CHUNK;
  const float4* src4 = (const float4*)src;
  unsigned* mycol = hist + t;

  constexpr int ITERS = CHUNK / (THREADS * 4);    // 16
  float4 c0 = src4[t];
  float4 c1 = src4[THREADS + t];
  #pragma unroll
  for (int it = 0; it < ITERS; ++it) {
    float4 cur = c0;
    c0 = c1;
    if (it + 2 < ITERS) c1 = src4[(it + 2) * THREADS + t];
    float vv[4] = {cur.x, cur.y, cur.z, cur.w};
    #pragma unroll
    for (int j = 0; j < 4; ++j) {
      float wv = vv[j] * 10.0f;                   // [0,10)
      float d  = wv - floorf(wv);                 // v_fract
      int   k  = (int)wv;                         // trunc == floor (wv >= 0)
      k = k > 9 ? 9 : k;                          // safety clamp
      float ex = __expf(d * -15.0f);              // e^{-xx}, xx = 15d
      float t1 = 1.0f + ex;                       // 1/sigma(xx)
      float t2 = fmaf(E15, ex, 1.0f);             // 1/sigma(xx-15)
      float r  = __builtin_amdgcn_rcpf(t1 * t2);  // one rcp -> both sigmoids
      unsigned qa = (unsigned)fmaf(r * t2, 255.0f, 0.5f);  // round(a*255)
      unsigned qb = (unsigned)fmaf(r * t1, 62.0f, 0.5f);   // round(b*62)
      unsigned pk = (((qa << 11) + qb) << 7) + 1u;
      atomicAdd(&mycol[k << 8], pk);              // ds_add_u32, fire-and-forget
    }
  }
  __syncthreads();

  // stage 1: 160 threads, each sums 16 columns of one bin (unpacked fields)
  if (t < 160) {
    const int bin = t >> 4, grp = t & 15;
    const uint4* hp = (const uint4*)(hist + (bin << 8) + (grp << 4));
    unsigned sa = 0, sb = 0, sc = 0;
    #pragma unroll
    for (int q = 0; q < 4; ++q) {
      uint4 u4 = hp[q];
      unsigned uu[4] = {u4.x, u4.y, u4.z, u4.w};
      #pragma unroll
      for (int e = 0; e < 4; ++e) {
        unsigned u = uu[e];
        sa += u >> 18; sb += (u >> 7) & 0x7FFu; sc += u & 0x7Fu;
      }
    }
    const int base = (bin * 16 + grp) * 3;
    red[base] = sa; red[base + 1] = sb; red[base + 2] = sc;
  }
  __syncthreads();

  // stage 2: 30 threads -> global integer atomics (deterministic)
  if (t < 30) {
    const int bin = t / 3, c = t - 3 * bin;
    unsigned s = 0;
    #pragma unroll
    for (int g = 0; g < 16; ++g) s += red[(bin * 16 + g) * 3 + c];
    atomicAdd(&G[plane * 30 + bin * 3 + c], s);
  }
}

__global__ __launch_bounds__(512) void soft_hist_loss(
    const unsigned* __restrict__ G, float* __restrict__ out)
{
  __shared__ float wred[8];
  const int t = threadIdx.x;
  float val = 0.0f;
  if (t < 480) {
    const int pc = t / 10;        // (batch,channel) 0..47
    const int i  = t - pc * 10;   // bin
    const unsigned* gx = G + pc * 30;
    const unsigned* gy = G + (pc + PLANES) * 30;
    // hist_i = A[i]/255 - B[i]/62 + B[i-1]/62 + C[i+1] - A[i+1]/255
    float hx = (float)gx[3 * i] * (1.0f / 255.0f)
             - (float)gx[3 * i + 1] * (1.0f / 62.0f)
             + (i > 0 ? (float)gx[3 * (i - 1) + 1] * (1.0f / 62.0f) : 0.0f)
             + (i < 9 ? (float)gx[3 * (i + 1) + 2]
                      - (float)gx[3 * (i + 1)] * (1.0f / 255.0f) : 0.0f);
    float hy = (float)gy[3 * i] * (1.0f / 255.0f)
             - (float)gy[3 * i + 1] * (1.0f / 62.0f)
             + (i > 0 ? (float)gy[3 * (i - 1) + 1] * (1.0f / 62.0f) : 0.0f)
             + (i < 9 ? (float)gy[3 * (i + 1) + 2]
                      - (float)gy[3 * (i + 1)] * (1.0f / 255.0f) : 0.0f);
    val = fabsf(hx - hy);
  }
  #pragma unroll
  for (int off = 32; off >= 1; off >>= 1) val += __shfl_xor(val, off, 64);
  if ((t & 63) == 0) wred[t >> 6] = val;
  __syncthreads();
  if (t == 0) {
    float s = 0.0f;
    #pragma unroll
    for (int w = 0; w < 8; ++w) s += wred[w];
    // loss = sum * (1/BINS) * (1/B) * 1e-4
    out[0] = s * 6.25e-7f;
  }
}

extern "C" void kernel_launch(void* const* d_in, const int* in_sizes, int n_in,
                              void* d_out, int out_size, void* d_ws, size_t ws_size,
                              hipStream_t stream) {
  const float* x = (const float*)d_in[0];
  const float* y = (const float*)d_in[1];
  unsigned* G = (unsigned*)d_ws;               // 96*30*4 = 11520 B
  hipMemsetAsync(d_ws, 0, 96 * 30 * sizeof(unsigned), stream);
  soft_hist_partial<<<NBLK, THREADS, 0, stream>>>(x, y, G);
  soft_hist_loss<<<1, 512, 0, stream>>>(G, (float*)d_out);
}